// Round 1
// baseline (932.935 us; speedup 1.0000x reference)
//
#include <hip/hip_runtime.h>

#define Bn 4
#define Hn 16
#define Tn 1024
#define Dn 64
#define N4 (Bn*Hn*Tn*Dn)   // 4,194,304 elements per projected tensor

// LAMBDA_INIT = 0.8 - 0.6*exp(-0.3*12) computed in double, rounded to f32
__device__ __constant__ float LAMBDA_INIT_F = 0.78360576653162445f;

// ---------------------------------------------------------------------------
// K0: lambda_full = exp(sum(lq1*lk1)) - exp(sum(lq2*lk2)) + LAMBDA_INIT
// ---------------------------------------------------------------------------
__global__ void k_lambda(const float* __restrict__ lq1, const float* __restrict__ lk1,
                         const float* __restrict__ lq2, const float* __restrict__ lk2,
                         float* __restrict__ lam_out) {
    int l = threadIdx.x;  // 64 threads
    float p1 = lq1[l] * lk1[l];
    float p2 = lq2[l] * lk2[l];
    #pragma unroll
    for (int m = 1; m < 64; m <<= 1) {
        p1 += __shfl_xor(p1, m);
        p2 += __shfl_xor(p2, m);
    }
    if (l == 0) lam_out[0] = expf(p1) - expf(p2) + LAMBDA_INIT_F;
}

// ---------------------------------------------------------------------------
// K1: per-head projection  dst[b,h,l,e] = sum_d src[b,h,l,d] * W[h,d,e]
// grid 1024 blocks (bh*16 + rowtile), 256 threads, 64 rows x 64 cols per block
// ---------------------------------------------------------------------------
__global__ __launch_bounds__(256) void k_proj(const float* __restrict__ src,
                                              const float* __restrict__ W,
                                              float* __restrict__ dst) {
    __shared__ float Qs[64][68];   // [row][d]
    __shared__ float Wt[64][68];   // [e][d]  (transposed from W[h][d][e])
    int t  = threadIdx.x;
    int bx = blockIdx.x;
    int bh = bx >> 4;
    int r0 = (bx & 15) * 64;
    int h  = bh & (Hn - 1);

    const float* sbase = src + (size_t)bh * Tn * Dn + (size_t)r0 * Dn;
    const float* wbase = W + (size_t)h * Dn * Dn;

    #pragma unroll
    for (int it = 0; it < 4; ++it) {
        int f4 = it * 256 + t;           // 0..1023
        int r  = f4 >> 4;
        int d0 = (f4 & 15) << 2;
        float4 v = *(const float4*)&sbase[(size_t)r * Dn + d0];
        *(float4*)&Qs[r][d0] = v;
        float4 w = *(const float4*)&wbase[(size_t)r * Dn + d0]; // r==d, d0==e0
        Wt[d0 + 0][r] = w.x; Wt[d0 + 1][r] = w.y;
        Wt[d0 + 2][r] = w.z; Wt[d0 + 3][r] = w.w;
    }
    __syncthreads();

    int tx = t & 15, ty = t >> 4;
    float acc[4][4];
    #pragma unroll
    for (int i = 0; i < 4; ++i)
        #pragma unroll
        for (int j = 0; j < 4; ++j) acc[i][j] = 0.f;

    #pragma unroll
    for (int d0 = 0; d0 < 64; d0 += 4) {
        float qa[4][4], wb[4][4];
        #pragma unroll
        for (int i = 0; i < 4; ++i) {
            float4 v = *(const float4*)&Qs[4 * ty + i][d0];
            qa[i][0] = v.x; qa[i][1] = v.y; qa[i][2] = v.z; qa[i][3] = v.w;
        }
        #pragma unroll
        for (int j = 0; j < 4; ++j) {
            float4 v = *(const float4*)&Wt[4 * tx + j][d0];
            wb[j][0] = v.x; wb[j][1] = v.y; wb[j][2] = v.z; wb[j][3] = v.w;
        }
        #pragma unroll
        for (int i = 0; i < 4; ++i)
            #pragma unroll
            for (int j = 0; j < 4; ++j)
                #pragma unroll
                for (int p = 0; p < 4; ++p)
                    acc[i][j] = fmaf(qa[i][p], wb[j][p], acc[i][j]);
    }

    float* dbase = dst + (size_t)bh * Tn * Dn + (size_t)r0 * Dn;
    #pragma unroll
    for (int i = 0; i < 4; ++i) {
        float4 o = make_float4(acc[i][0], acc[i][1], acc[i][2], acc[i][3]);
        *(float4*)&dbase[(size_t)(4 * ty + i) * Dn + 4 * tx] = o;
    }
}

// ---------------------------------------------------------------------------
// K2: 128-row block sums of kf:  bs[bh,br,j,d] = sum_{r in block j} kf[bh,j*128+r,d]
// grid 1024 (bh*16 + br*8 + j), 256 threads
// ---------------------------------------------------------------------------
__global__ void k_blocksum(const float* __restrict__ kf1, const float* __restrict__ kf2,
                           float* __restrict__ bs) {
    __shared__ float red[4][64];
    int t  = threadIdx.x;
    int bx = blockIdx.x;
    int j  = bx & 7;
    int br = (bx >> 3) & 1;
    int bh = bx >> 4;
    const float* kf = (br ? kf2 : kf1) + (size_t)bh * Tn * Dn + (size_t)j * 128 * Dn;
    int d = t & 63, rg = t >> 6;
    float p = 0.f;
    #pragma unroll 4
    for (int r = 0; r < 32; ++r) p += kf[(size_t)(rg * 32 + r) * Dn + d];
    red[rg][d] = p;
    __syncthreads();
    if (rg == 0)
        bs[(((size_t)bh * 2 + br) * 8 + j) * 64 + d] =
            red[0][d] + red[1][d] + red[2][d] + red[3][d];
}

// ---------------------------------------------------------------------------
// K3: exclusive prefix over the 8 block sums -> kc[bh,br,j,d]
// grid 128 (bh*2+br), 64 threads
// ---------------------------------------------------------------------------
__global__ void k_prefix(const float* __restrict__ bs, float* __restrict__ kc) {
    int bx = blockIdx.x;
    int br = bx & 1, bh = bx >> 1;
    int d = threadIdx.x;
    float run = 0.f;
    for (int j = 0; j < 8; ++j) {
        size_t idx = (((size_t)bh * 2 + br) * 8 + j) * 64 + d;
        kc[idx] = run;
        run += bs[idx];
    }
}

// ---------------------------------------------------------------------------
// K4: main — per (bh, rowtile of 128):
//   diag-chunk compute -> masked rowsum partials (accs kept live)
//   + qf . Kcum(exclusive)  + single super-diagonal edge element
//   -> inv_s; then write diag (from live accs), full chunks, zero-fill.
// ---------------------------------------------------------------------------
__global__ __launch_bounds__(256, 2) void k_main(
    const float* __restrict__ qf1, const float* __restrict__ kf1,
    const float* __restrict__ qf2, const float* __restrict__ kf2,
    const float* __restrict__ kc,  const float* __restrict__ lamp,
    float* __restrict__ out) {

    __shared__ float As[2][8][132];   // [br][k][row]
    __shared__ float Bsh[2][8][132];  // [br][k][col]
    __shared__ float s_red[2][128];
    __shared__ float inv_s[2][128];
    __shared__ float e_val[2];

    int t  = threadIdx.x;
    int bx = blockIdx.x;
    int bh = bx >> 3;
    int rt = 7 - (bx & 7);         // big tiles dispatched first
    int r0 = rt * 128;
    int tx = t & 15, ty = t >> 4;

    const float lam = lamp[0];

    const float* qg[2] = { qf1 + (size_t)bh * Tn * Dn, qf2 + (size_t)bh * Tn * Dn };
    const float* kg[2] = { kf1 + (size_t)bh * Tn * Dn, kf2 + (size_t)bh * Tn * Dn };

    float acc[2][8][8];

    // ---- chunk compute: acc[br][i][j] += qf[r0+8ty+i] . kf[colbase+8tx+j] ----
    auto compute_chunk = [&](int colbase) {
        #pragma unroll
        for (int br = 0; br < 2; ++br)
            #pragma unroll
            for (int i = 0; i < 8; ++i)
                #pragma unroll
                for (int j = 0; j < 8; ++j) acc[br][i][j] = 0.f;

        for (int ks = 0; ks < 8; ++ks) {
            int kbase = ks * 8;
            __syncthreads();   // WAR guard on As/Bsh
            {
                int rc = t >> 1, k0 = (t & 1) << 2;
                float4 a0 = *(const float4*)&qg[0][(size_t)(r0 + rc) * Dn + kbase + k0];
                As[0][k0 + 0][rc] = a0.x; As[0][k0 + 1][rc] = a0.y;
                As[0][k0 + 2][rc] = a0.z; As[0][k0 + 3][rc] = a0.w;
                float4 a1 = *(const float4*)&qg[1][(size_t)(r0 + rc) * Dn + kbase + k0];
                As[1][k0 + 0][rc] = a1.x; As[1][k0 + 1][rc] = a1.y;
                As[1][k0 + 2][rc] = a1.z; As[1][k0 + 3][rc] = a1.w;
                float4 b0 = *(const float4*)&kg[0][(size_t)(colbase + rc) * Dn + kbase + k0];
                Bsh[0][k0 + 0][rc] = b0.x; Bsh[0][k0 + 1][rc] = b0.y;
                Bsh[0][k0 + 2][rc] = b0.z; Bsh[0][k0 + 3][rc] = b0.w;
                float4 b1 = *(const float4*)&kg[1][(size_t)(colbase + rc) * Dn + kbase + k0];
                Bsh[1][k0 + 0][rc] = b1.x; Bsh[1][k0 + 1][rc] = b1.y;
                Bsh[1][k0 + 2][rc] = b1.z; Bsh[1][k0 + 3][rc] = b1.w;
            }
            __syncthreads();
            #pragma unroll
            for (int kk = 0; kk < 8; ++kk) {
                float a0[8], a1[8], b0[8], b1[8];
                float4 v;
                v = *(const float4*)&As[0][kk][8 * ty];     a0[0]=v.x; a0[1]=v.y; a0[2]=v.z; a0[3]=v.w;
                v = *(const float4*)&As[0][kk][8 * ty + 4]; a0[4]=v.x; a0[5]=v.y; a0[6]=v.z; a0[7]=v.w;
                v = *(const float4*)&As[1][kk][8 * ty];     a1[0]=v.x; a1[1]=v.y; a1[2]=v.z; a1[3]=v.w;
                v = *(const float4*)&As[1][kk][8 * ty + 4]; a1[4]=v.x; a1[5]=v.y; a1[6]=v.z; a1[7]=v.w;
                v = *(const float4*)&Bsh[0][kk][8 * tx];     b0[0]=v.x; b0[1]=v.y; b0[2]=v.z; b0[3]=v.w;
                v = *(const float4*)&Bsh[0][kk][8 * tx + 4]; b0[4]=v.x; b0[5]=v.y; b0[6]=v.z; b0[7]=v.w;
                v = *(const float4*)&Bsh[1][kk][8 * tx];     b1[0]=v.x; b1[1]=v.y; b1[2]=v.z; b1[3]=v.w;
                v = *(const float4*)&Bsh[1][kk][8 * tx + 4]; b1[4]=v.x; b1[5]=v.y; b1[6]=v.z; b1[7]=v.w;
                #pragma unroll
                for (int i = 0; i < 8; ++i)
                    #pragma unroll
                    for (int j = 0; j < 8; ++j) {
                        acc[0][i][j] = fmaf(a0[i], b0[j], acc[0][i][j]);
                        acc[1][i][j] = fmaf(a1[i], b1[j], acc[1][i][j]);
                    }
            }
        }
    };

    // ---- normalized write of current accs at colbase ----
    auto write_chunk = [&](int colbase) {
        #pragma unroll
        for (int i = 0; i < 8; ++i) {
            int row = 8 * ty + i;
            float i1 = inv_s[0][row], i2 = inv_s[1][row];
            float4 o0, o1;
            o0.x = acc[0][i][0] * i1 - lam * (acc[1][i][0] * i2);
            o0.y = acc[0][i][1] * i1 - lam * (acc[1][i][1] * i2);
            o0.z = acc[0][i][2] * i1 - lam * (acc[1][i][2] * i2);
            o0.w = acc[0][i][3] * i1 - lam * (acc[1][i][3] * i2);
            o1.x = acc[0][i][4] * i1 - lam * (acc[1][i][4] * i2);
            o1.y = acc[0][i][5] * i1 - lam * (acc[1][i][5] * i2);
            o1.z = acc[0][i][6] * i1 - lam * (acc[1][i][6] * i2);
            o1.w = acc[0][i][7] * i1 - lam * (acc[1][i][7] * i2);
            size_t base = ((size_t)bh * Tn + r0 + row) * Tn + colbase + 8 * tx;
            *(float4*)&out[base] = o0;
            *(float4*)&out[base + 4] = o1;
        }
    };

    // ================= P1: diagonal chunk =================
    compute_chunk(r0);

    // mask: keep col <= row+1 (local coords, same offset both sides)
    #pragma unroll
    for (int i = 0; i < 8; ++i)
        #pragma unroll
        for (int j = 0; j < 8; ++j)
            if (8 * tx + j > 8 * ty + i + 1) { acc[0][i][j] = 0.f; acc[1][i][j] = 0.f; }

    // ================= P2: masked row-sum partials =================
    #pragma unroll
    for (int br = 0; br < 2; ++br)
        #pragma unroll
        for (int i = 0; i < 8; ++i) {
            float rs = 0.f;
            #pragma unroll
            for (int j = 0; j < 8; ++j) rs += acc[br][i][j];
            #pragma unroll
            for (int m = 1; m < 16; m <<= 1) rs += __shfl_xor(rs, m);
            if (tx == 0) s_red[br][8 * ty + i] = rs;
        }
    __syncthreads();

    // ================= P3: Kcum dot + edge + reciprocal =================
    {
        int row = t & 127;
        int br7 = t >> 7;
        const float* qp = br7 ? qg[1] : qg[0];
        const float* qrow = qp + (size_t)(r0 + row) * Dn;
        const float* kcp = kc + (((size_t)bh * 2 + br7) * 8 + rt) * 64;
        float dotv = 0.f;
        #pragma unroll
        for (int d0 = 0; d0 < 64; d0 += 4) {
            float4 a = *(const float4*)&qrow[d0];
            float4 b = *(const float4*)&kcp[d0];
            dotv = fmaf(a.x, b.x, dotv); dotv = fmaf(a.y, b.y, dotv);
            dotv = fmaf(a.z, b.z, dotv); dotv = fmaf(a.w, b.w, dotv);
        }
        if (row == 127 && r0 + 128 < Tn) {
            const float* kp = br7 ? kg[1] : kg[0];
            const float* krow = kp + (size_t)(r0 + 128) * Dn;
            float ev = 0.f;
            #pragma unroll
            for (int d0 = 0; d0 < 64; d0 += 4) {
                float4 a = *(const float4*)&qrow[d0];
                float4 b = *(const float4*)&krow[d0];
                ev = fmaf(a.x, b.x, ev); ev = fmaf(a.y, b.y, ev);
                ev = fmaf(a.z, b.z, ev); ev = fmaf(a.w, b.w, ev);
            }
            e_val[br7] = ev;
            dotv += ev;
        }
        float s = s_red[br7][row] + dotv;
        inv_s[br7][row] = 1.0f / s;
    }
    __syncthreads();

    // ================= P4a: write diagonal chunk from live accs =================
    write_chunk(r0);

    // ================= P4b: full chunks + zero fill =================
    for (int c = 0; c < 8; ++c) {
        if (c == rt) continue;
        if (c < rt) {
            compute_chunk(c * 128);   // fully valid, no mask
            write_chunk(c * 128);
        } else {
            float4 z = make_float4(0.f, 0.f, 0.f, 0.f);
            #pragma unroll
            for (int i = 0; i < 8; ++i) {
                size_t base = ((size_t)bh * Tn + r0 + 8 * ty + i) * Tn + c * 128 + 8 * tx;
                float4 o0 = z;
                if (c == rt + 1 && ty == 15 && i == 7 && tx == 0) {
                    // the single super-diagonal element (row r0+127, col r0+128)
                    o0.x = e_val[0] * inv_s[0][127] - lam * (e_val[1] * inv_s[1][127]);
                }
                *(float4*)&out[base] = o0;
                *(float4*)&out[base + 4] = z;
            }
        }
    }
}

// ---------------------------------------------------------------------------
extern "C" void kernel_launch(void* const* d_in, const int* in_sizes, int n_in,
                              void* d_out, int out_size, void* d_ws, size_t ws_size,
                              hipStream_t stream) {
    const float* q   = (const float*)d_in[0];
    const float* k   = (const float*)d_in[1];
    const float* W1q = (const float*)d_in[2];
    const float* W1k = (const float*)d_in[3];
    const float* W2q = (const float*)d_in[4];
    const float* W2k = (const float*)d_in[5];
    const float* lq1 = (const float*)d_in[6];
    const float* lk1 = (const float*)d_in[7];
    const float* lq2 = (const float*)d_in[8];
    const float* lk2 = (const float*)d_in[9];
    float* out = (float*)d_out;
    float* ws  = (float*)d_ws;

    float* qf1 = ws;
    float* kf1 = ws + (size_t)N4;
    float* qf2 = ws + 2 * (size_t)N4;
    float* kf2 = ws + 3 * (size_t)N4;
    float* bs  = ws + 4 * (size_t)N4;          // 64*2*8*64 = 65536 floats
    float* kc  = bs + 65536;                   // 65536 floats
    float* lamp = kc + 65536;                  // 1 float

    k_lambda<<<1, 64, 0, stream>>>(lq1, lk1, lq2, lk2, lamp);
    k_proj<<<1024, 256, 0, stream>>>(q, W1q, qf1);
    k_proj<<<1024, 256, 0, stream>>>(k, W1k, kf1);
    k_proj<<<1024, 256, 0, stream>>>(q, W2q, qf2);
    k_proj<<<1024, 256, 0, stream>>>(k, W2k, kf2);
    k_blocksum<<<1024, 256, 0, stream>>>(kf1, kf2, bs);
    k_prefix<<<128, 64, 0, stream>>>(bs, kc);
    k_main<<<512, 256, 0, stream>>>(qf1, kf1, qf2, kf2, kc, lamp, out);
}

// Round 3
// 602.619 us; speedup vs baseline: 1.5481x; 1.5481x over previous
//
#include <hip/hip_runtime.h>

#define Bn 4
#define Hn 16
#define Tn 1024
#define Dn 64
#define N4 (Bn*Hn*Tn*Dn)   // 4,194,304 elements per projected tensor

// LAMBDA_INIT = 0.8 - 0.6*exp(-0.3*12)
__device__ __constant__ float LAMBDA_INIT_F = 0.78360576653162445f;

// ---------------------------------------------------------------------------
// K0: lambda_full = exp(sum(lq1*lk1)) - exp(sum(lq2*lk2)) + LAMBDA_INIT
// ---------------------------------------------------------------------------
__global__ void k_lambda(const float* __restrict__ lq1, const float* __restrict__ lk1,
                         const float* __restrict__ lq2, const float* __restrict__ lk2,
                         float* __restrict__ lam_out) {
    int l = threadIdx.x;  // 64 threads
    float p1 = lq1[l] * lk1[l];
    float p2 = lq2[l] * lk2[l];
    #pragma unroll
    for (int m = 1; m < 64; m <<= 1) {
        p1 += __shfl_xor(p1, m);
        p2 += __shfl_xor(p2, m);
    }
    if (l == 0) lam_out[0] = expf(p1) - expf(p2) + LAMBDA_INIT_F;
}

// ---------------------------------------------------------------------------
// K1: per-head projection  dst[b,h,l,e] = sum_d src[b,h,l,d] * W[h,d,e]
// grid 1024 blocks (bh*16 + rowtile), 256 threads, 64 rows x 64 cols per block
// ---------------------------------------------------------------------------
__global__ __launch_bounds__(256) void k_proj(const float* __restrict__ src,
                                              const float* __restrict__ W,
                                              float* __restrict__ dst) {
    __shared__ float Qs[64][68];   // [row][d]
    __shared__ float Wt[64][68];   // [e][d]  (transposed from W[h][d][e])
    int t  = threadIdx.x;
    int bx = blockIdx.x;
    int bh = bx >> 4;
    int r0 = (bx & 15) * 64;
    int h  = bh & (Hn - 1);

    const float* sbase = src + (size_t)bh * Tn * Dn + (size_t)r0 * Dn;
    const float* wbase = W + (size_t)h * Dn * Dn;

    #pragma unroll
    for (int it = 0; it < 4; ++it) {
        int f4 = it * 256 + t;           // 0..1023
        int r  = f4 >> 4;
        int d0 = (f4 & 15) << 2;
        float4 v = *(const float4*)&sbase[(size_t)r * Dn + d0];
        *(float4*)&Qs[r][d0] = v;
        float4 w = *(const float4*)&wbase[(size_t)r * Dn + d0]; // r==d, d0==e0
        Wt[d0 + 0][r] = w.x; Wt[d0 + 1][r] = w.y;
        Wt[d0 + 2][r] = w.z; Wt[d0 + 3][r] = w.w;
    }
    __syncthreads();

    int tx = t & 15, ty = t >> 4;
    float acc[4][4];
    #pragma unroll
    for (int i = 0; i < 4; ++i)
        #pragma unroll
        for (int j = 0; j < 4; ++j) acc[i][j] = 0.f;

    #pragma unroll
    for (int d0 = 0; d0 < 64; d0 += 4) {
        float qa[4][4], wb[4][4];
        #pragma unroll
        for (int i = 0; i < 4; ++i) {
            float4 v = *(const float4*)&Qs[4 * ty + i][d0];
            qa[i][0] = v.x; qa[i][1] = v.y; qa[i][2] = v.z; qa[i][3] = v.w;
        }
        #pragma unroll
        for (int j = 0; j < 4; ++j) {
            float4 v = *(const float4*)&Wt[4 * tx + j][d0];
            wb[j][0] = v.x; wb[j][1] = v.y; wb[j][2] = v.z; wb[j][3] = v.w;
        }
        #pragma unroll
        for (int i = 0; i < 4; ++i)
            #pragma unroll
            for (int j = 0; j < 4; ++j)
                #pragma unroll
                for (int p = 0; p < 4; ++p)
                    acc[i][j] = fmaf(qa[i][p], wb[j][p], acc[i][j]);
    }

    float* dbase = dst + (size_t)bh * Tn * Dn + (size_t)r0 * Dn;
    #pragma unroll
    for (int i = 0; i < 4; ++i) {
        float4 o = make_float4(acc[i][0], acc[i][1], acc[i][2], acc[i][3]);
        *(float4*)&dbase[(size_t)(4 * ty + i) * Dn + 4 * tx] = o;
    }
}

// ---------------------------------------------------------------------------
// K2: 128-row block sums of kf:  bs[bh,br,j,d] = sum_{r in block j} kf[bh,j*128+r,d]
// grid 1024 (bh*16 + br*8 + j), 256 threads
// ---------------------------------------------------------------------------
__global__ void k_blocksum(const float* __restrict__ kf1, const float* __restrict__ kf2,
                           float* __restrict__ bs) {
    __shared__ float red[4][64];
    int t  = threadIdx.x;
    int bx = blockIdx.x;
    int j  = bx & 7;
    int br = (bx >> 3) & 1;
    int bh = bx >> 4;
    const float* kf = (br ? kf2 : kf1) + (size_t)bh * Tn * Dn + (size_t)j * 128 * Dn;
    int d = t & 63, rg = t >> 6;
    float p = 0.f;
    #pragma unroll 4
    for (int r = 0; r < 32; ++r) p += kf[(size_t)(rg * 32 + r) * Dn + d];
    red[rg][d] = p;
    __syncthreads();
    if (rg == 0)
        bs[(((size_t)bh * 2 + br) * 8 + j) * 64 + d] =
            red[0][d] + red[1][d] + red[2][d] + red[3][d];
}

// ---------------------------------------------------------------------------
// K3: exclusive prefix over the 8 block sums -> kc[bh,br,j,d]
// grid 128 (bh*2+br), 64 threads
// ---------------------------------------------------------------------------
__global__ void k_prefix(const float* __restrict__ bs, float* __restrict__ kc) {
    int bx = blockIdx.x;
    int br = bx & 1, bh = bx >> 1;
    int d = threadIdx.x;
    float run = 0.f;
    for (int j = 0; j < 8; ++j) {
        size_t idx = (((size_t)bh * 2 + br) * 8 + j) * 64 + d;
        kc[idx] = run;
        run += bs[idx];
    }
}

// ---------------------------------------------------------------------------
// K_s: inv_s[bh,br,row] = 1 / ( qf[row] . Pref[min(row+1, T-1)] )
// where Pref[t] = sum_{k<=t} kf[k]  (the tril(diag=1) masked row sum, factored)
// grid 256 = bh(64) x br(2) x half(2); 256 threads; wave g walks chunk
// j = half*4+g of 128 rows serially, seeded from the exclusive chunk prefix kc.
// ---------------------------------------------------------------------------
__global__ __launch_bounds__(256) void k_s(
    const float* __restrict__ qf1, const float* __restrict__ kf1,
    const float* __restrict__ qf2, const float* __restrict__ kf2,
    const float* __restrict__ kc,  float* __restrict__ inv_out) {
    int bx = blockIdx.x;
    int half = bx & 1, br = (bx >> 1) & 1, bh = bx >> 2;
    int g = threadIdx.x >> 6, d = threadIdx.x & 63;
    int j = half * 4 + g;                  // chunk 0..7
    const float* qf = (br ? qf2 : qf1) + (size_t)bh * Tn * Dn;
    const float* kf = (br ? kf2 : kf1) + (size_t)bh * Tn * Dn;
    float run = kc[(((size_t)bh * 2 + br) * 8 + j) * 64 + d];  // sum rows < j*128
    int R0 = j * 128;
    float* inv = inv_out + ((size_t)bh * 2 + br) * Tn;

    #pragma unroll 4
    for (int step = 0; step <= 128; ++step) {
        int r = R0 + step;
        if (r < Tn) run += kf[(size_t)r * Dn + d];   // run = Pref[r] (or Pref[1023] at r=1024)
        if (step >= 1) {
            int rr = r - 1;
            float dv = qf[(size_t)rr * Dn + d] * run;
            #pragma unroll
            for (int m = 1; m < 64; m <<= 1) dv += __shfl_xor(dv, m);
            if (d == 0) inv[rr] = 1.0f / dv;
        }
    }
}

// ---------------------------------------------------------------------------
// K_tile: one 128x128 output tile per block, branches FUSED into one K=128
// GEMM: A' rows pre-scaled by {i1[r], -lam*i2[r]} at LDS-stage time, so
//   out = A'.B'^T  directly (no per-element normalize at write).
//   c <  rt : full tile GEMM, write
//   c == rt : diagonal tile GEMM, mask (col<=row+1 local), write
//   c >  rt : zero fill; if c==rt+1 also the single super-diagonal element
// grid 4096 = bh(64) x rt(8) x c(8), XCD-chunk swizzled.
// ---------------------------------------------------------------------------
__global__ __launch_bounds__(256, 4) void k_tile(
    const float* __restrict__ qf1, const float* __restrict__ kf1,
    const float* __restrict__ qf2, const float* __restrict__ kf2,
    const float* __restrict__ inv_g, const float* __restrict__ lamp,
    float* __restrict__ out) {

    __shared__ float As[16][132];   // [k][row]  pre-scaled A slice
    __shared__ float Bs[16][192];   // [k][swz(col)]  swz(c)=c+4*(c>>3)
    __shared__ float scl[2][128];   // {i1[row], -lam*i2[row]}
    __shared__ float e_sh[2];

    int t  = threadIdx.x;
    // XCD-chunk swizzle: 4096 blocks, 8 XCDs, 512 per XCD (bijective)
    int vid = (blockIdx.x & 7) * 512 + (blockIdx.x >> 3);
    int bh = vid >> 6;
    int tile = vid & 63;
    int rt = tile >> 3, c = tile & 7;
    int r0 = rt * 128, cb = c * 128;
    int tx = t & 15, ty = t >> 4;

    const float lam = lamp[0];
    const float* qg0 = qf1 + (size_t)bh * Tn * Dn;
    const float* qg1 = qf2 + (size_t)bh * Tn * Dn;
    const float* kg0 = kf1 + (size_t)bh * Tn * Dn;
    const float* kg1 = kf2 + (size_t)bh * Tn * Dn;

    // ---------------- fill role ----------------
    if (c > rt) {
        float ev = 0.f;
        if (c == rt + 1) {
            if (t < 128) {
                int br = t >> 6, d = t & 63;
                const float* qp = br ? qg1 : qg0;
                const float* kp = br ? kg1 : kg0;
                float p = qp[(size_t)(r0 + 127) * Dn + d] * kp[(size_t)cb * Dn + d];
                #pragma unroll
                for (int m = 1; m < 64; m <<= 1) p += __shfl_xor(p, m);
                if (d == 0) e_sh[br] = p;
            }
            __syncthreads();
            float i1 = inv_g[((size_t)bh * 2 + 0) * Tn + r0 + 127];
            float i2 = inv_g[((size_t)bh * 2 + 1) * Tn + r0 + 127];
            ev = e_sh[0] * i1 - lam * (e_sh[1] * i2);
        }
        float4 z = make_float4(0.f, 0.f, 0.f, 0.f);
        #pragma unroll
        for (int i = 0; i < 8; ++i) {
            size_t base = ((size_t)bh * Tn + r0 + 8 * ty + i) * Tn + cb + 8 * tx;
            float4 o0 = z;
            if (ty == 15 && i == 7 && tx == 0) o0.x = ev;  // ev==0 unless c==rt+1
            *(float4*)&out[base] = o0;
            *(float4*)&out[base + 4] = z;
        }
        return;
    }

    // ---------------- compute role ----------------
    // stage row scales: branch1 -> i1[row], branch2 -> -lam*i2[row]
    {
        int br = t >> 7, row = t & 127;
        float iv = inv_g[((size_t)bh * 2 + br) * Tn + r0 + row];
        scl[br][row] = br ? (-lam * iv) : iv;
    }

    float acc[8][8];
    #pragma unroll
    for (int i = 0; i < 8; ++i)
        #pragma unroll
        for (int j = 0; j < 8; ++j) acc[i][j] = 0.f;

    int rc  = t & 127;                 // staged row/col
    int kl  = (t >> 7) << 3;           // 0 or 8: k sub-slice within the 16
    int rcs = rc + ((rc >> 3) << 2);   // swizzled col index

    for (int ks = 0; ks < 8; ++ks) {   // 8 slices of 16 k (branch1: 0..3, branch2: 4..7)
        const float* qsrc = (ks < 4) ? qg0 : qg1;
        const float* ksrc = (ks < 4) ? kg0 : kg1;
        int kbeg = ((ks & 3) << 4) + kl;
        __syncthreads();   // WAR guard on As/Bs (first iter: scl visibility)
        {
            float s = scl[ks >> 2][rc];
            const float* qrow = &qsrc[(size_t)(r0 + rc) * Dn + kbeg];
            float4 a0 = *(const float4*)qrow;
            float4 a1 = *(const float4*)(qrow + 4);
            As[kl + 0][rc] = a0.x * s; As[kl + 1][rc] = a0.y * s;
            As[kl + 2][rc] = a0.z * s; As[kl + 3][rc] = a0.w * s;
            As[kl + 4][rc] = a1.x * s; As[kl + 5][rc] = a1.y * s;
            As[kl + 6][rc] = a1.z * s; As[kl + 7][rc] = a1.w * s;
            const float* krow = &ksrc[(size_t)(cb + rc) * Dn + kbeg];
            float4 b0 = *(const float4*)krow;
            float4 b1 = *(const float4*)(krow + 4);
            Bs[kl + 0][rcs] = b0.x; Bs[kl + 1][rcs] = b0.y;
            Bs[kl + 2][rcs] = b0.z; Bs[kl + 3][rcs] = b0.w;
            Bs[kl + 4][rcs] = b1.x; Bs[kl + 5][rcs] = b1.y;
            Bs[kl + 6][rcs] = b1.z; Bs[kl + 7][rcs] = b1.w;
        }
        __syncthreads();
        int txs = 12 * tx;   // swz(8*tx)
        #pragma unroll
        for (int kk = 0; kk < 16; ++kk) {
            float av[8], bv[8];
            float4 v;
            v = *(const float4*)&As[kk][8 * ty];     av[0]=v.x; av[1]=v.y; av[2]=v.z; av[3]=v.w;
            v = *(const float4*)&As[kk][8 * ty + 4]; av[4]=v.x; av[5]=v.y; av[6]=v.z; av[7]=v.w;
            v = *(const float4*)&Bs[kk][txs];        bv[0]=v.x; bv[1]=v.y; bv[2]=v.z; bv[3]=v.w;
            v = *(const float4*)&Bs[kk][txs + 4];    bv[4]=v.x; bv[5]=v.y; bv[6]=v.z; bv[7]=v.w;
            #pragma unroll
            for (int i = 0; i < 8; ++i)
                #pragma unroll
                for (int j = 0; j < 8; ++j)
                    acc[i][j] = fmaf(av[i], bv[j], acc[i][j]);
        }
    }

    // diagonal mask: keep col <= row+1 (local coords, same offset both sides)
    if (c == rt) {
        #pragma unroll
        for (int i = 0; i < 8; ++i)
            #pragma unroll
            for (int j = 0; j < 8; ++j)
                if (8 * tx + j > 8 * ty + i + 1) acc[i][j] = 0.f;
    }

    // write (already normalized & combined)
    #pragma unroll
    for (int i = 0; i < 8; ++i) {
        float4 o0 = make_float4(acc[i][0], acc[i][1], acc[i][2], acc[i][3]);
        float4 o1 = make_float4(acc[i][4], acc[i][5], acc[i][6], acc[i][7]);
        size_t base = ((size_t)bh * Tn + r0 + 8 * ty + i) * Tn + cb + 8 * tx;
        *(float4*)&out[base] = o0;
        *(float4*)&out[base + 4] = o1;
    }
}

// ---------------------------------------------------------------------------
extern "C" void kernel_launch(void* const* d_in, const int* in_sizes, int n_in,
                              void* d_out, int out_size, void* d_ws, size_t ws_size,
                              hipStream_t stream) {
    const float* q   = (const float*)d_in[0];
    const float* k   = (const float*)d_in[1];
    const float* W1q = (const float*)d_in[2];
    const float* W1k = (const float*)d_in[3];
    const float* W2q = (const float*)d_in[4];
    const float* W2k = (const float*)d_in[5];
    const float* lq1 = (const float*)d_in[6];
    const float* lk1 = (const float*)d_in[7];
    const float* lq2 = (const float*)d_in[8];
    const float* lk2 = (const float*)d_in[9];
    float* out = (float*)d_out;
    float* ws  = (float*)d_ws;

    float* qf1 = ws;
    float* kf1 = ws + (size_t)N4;
    float* qf2 = ws + 2 * (size_t)N4;
    float* kf2 = ws + 3 * (size_t)N4;
    float* bs  = ws + 4 * (size_t)N4;          // 64*2*8*64 = 65536 floats
    float* kc  = bs + 65536;                   // 65536 floats
    float* lamp = kc + 65536;                  // 1 float (padded to 64)
    float* inv_s = lamp + 64;                  // 64*2*1024 = 131072 floats

    k_lambda<<<1, 64, 0, stream>>>(lq1, lk1, lq2, lk2, lamp);
    k_proj<<<1024, 256, 0, stream>>>(q, W1q, qf1);
    k_proj<<<1024, 256, 0, stream>>>(k, W1k, kf1);
    k_proj<<<1024, 256, 0, stream>>>(q, W2q, qf2);
    k_proj<<<1024, 256, 0, stream>>>(k, W2k, kf2);
    k_blocksum<<<1024, 256, 0, stream>>>(kf1, kf2, bs);
    k_prefix<<<128, 64, 0, stream>>>(bs, kc);
    k_s<<<256, 256, 0, stream>>>(qf1, kf1, qf2, kf2, kc, inv_s);
    k_tile<<<4096, 256, 0, stream>>>(qf1, kf1, qf2, kf2, inv_s, lamp, out);
}

// Round 4
// 491.029 us; speedup vs baseline: 1.9000x; 1.2273x over previous
//
#include <hip/hip_runtime.h>

#define Bn 4
#define Hn 16
#define Tn 1024
#define Dn 64
#define N4 (Bn*Hn*Tn*Dn)   // 4,194,304 elements per projected tensor
#define TD (Tn*Dn)

typedef __attribute__((ext_vector_type(8))) short bf16x8;
typedef __attribute__((ext_vector_type(4))) float f32x4;

// LAMBDA_INIT = 0.8 - 0.6*exp(-0.3*12)
__device__ __constant__ float LAMBDA_INIT_F = 0.78360576653162445f;

__device__ inline unsigned short bf16_rne(float x) {
    unsigned u = __float_as_uint(x);
    unsigned r = (u + 0x7FFFu + ((u >> 16) & 1u)) >> 16;
    return (unsigned short)r;
}
__device__ inline float bf16_to_f(unsigned short h) {
    return __uint_as_float(((unsigned)h) << 16);
}

// ---------------------------------------------------------------------------
// K0: lambda_full
// ---------------------------------------------------------------------------
__global__ void k_lambda(const float* __restrict__ lq1, const float* __restrict__ lk1,
                         const float* __restrict__ lq2, const float* __restrict__ lk2,
                         float* __restrict__ lam_out) {
    int l = threadIdx.x;  // 64 threads
    float p1 = lq1[l] * lk1[l];
    float p2 = lq2[l] * lk2[l];
    #pragma unroll
    for (int m = 1; m < 64; m <<= 1) {
        p1 += __shfl_xor(p1, m);
        p2 += __shfl_xor(p2, m);
    }
    if (l == 0) lam_out[0] = expf(p1) - expf(p2) + LAMBDA_INIT_F;
}

// ---------------------------------------------------------------------------
// K1: all 4 projections in one launch. idx = bx&3 selects (src, W, dst).
// Also emits bf16 hi/lo split tensors for the MFMA main kernel.
// grid 4096, 256 threads, 64 rows x 64 cols per block.
// ---------------------------------------------------------------------------
__global__ __launch_bounds__(256) void k_proj4(
    const float* __restrict__ q, const float* __restrict__ k,
    const float* __restrict__ W1q, const float* __restrict__ W1k,
    const float* __restrict__ W2q, const float* __restrict__ W2k,
    float* __restrict__ qf1, float* __restrict__ kf1,
    float* __restrict__ qf2, float* __restrict__ kf2,
    unsigned short* __restrict__ qh1, unsigned short* __restrict__ ql1,
    unsigned short* __restrict__ kh1, unsigned short* __restrict__ kl1,
    unsigned short* __restrict__ qh2, unsigned short* __restrict__ ql2,
    unsigned short* __restrict__ kh2, unsigned short* __restrict__ kl2) {

    __shared__ float Qs[64][68];   // [row][d]
    __shared__ float Wt[64][68];   // [e][d]

    int t  = threadIdx.x;
    int bx = blockIdx.x;
    int idx  = bx & 3;
    int tile = bx >> 2;
    int bh = tile >> 4;
    int r0 = (tile & 15) * 64;
    int h  = bh & (Hn - 1);

    const float* src = (idx & 1) ? k : q;
    const float* W = (idx == 0) ? W1q : (idx == 1) ? W1k : (idx == 2) ? W2q : W2k;
    float* dst = (idx == 0) ? qf1 : (idx == 1) ? kf1 : (idx == 2) ? qf2 : kf2;
    unsigned short* dsth = (idx == 0) ? qh1 : (idx == 1) ? kh1 : (idx == 2) ? qh2 : kh2;
    unsigned short* dstl = (idx == 0) ? ql1 : (idx == 1) ? kl1 : (idx == 2) ? ql2 : kl2;

    const float* sbase = src + (size_t)bh * TD + (size_t)r0 * Dn;
    const float* wbase = W + (size_t)h * Dn * Dn;

    #pragma unroll
    for (int it = 0; it < 4; ++it) {
        int f4 = it * 256 + t;           // 0..1023
        int r  = f4 >> 4;
        int d0 = (f4 & 15) << 2;
        float4 v = *(const float4*)&sbase[(size_t)r * Dn + d0];
        *(float4*)&Qs[r][d0] = v;
        float4 w = *(const float4*)&wbase[(size_t)r * Dn + d0]; // r==d, d0==e0
        Wt[d0 + 0][r] = w.x; Wt[d0 + 1][r] = w.y;
        Wt[d0 + 2][r] = w.z; Wt[d0 + 3][r] = w.w;
    }
    __syncthreads();

    int tx = t & 15, ty = t >> 4;
    float acc[4][4];
    #pragma unroll
    for (int i = 0; i < 4; ++i)
        #pragma unroll
        for (int j = 0; j < 4; ++j) acc[i][j] = 0.f;

    #pragma unroll
    for (int d0 = 0; d0 < 64; d0 += 4) {
        float qa[4][4], wb[4][4];
        #pragma unroll
        for (int i = 0; i < 4; ++i) {
            float4 v = *(const float4*)&Qs[4 * ty + i][d0];
            qa[i][0] = v.x; qa[i][1] = v.y; qa[i][2] = v.z; qa[i][3] = v.w;
        }
        #pragma unroll
        for (int j = 0; j < 4; ++j) {
            float4 v = *(const float4*)&Wt[4 * tx + j][d0];
            wb[j][0] = v.x; wb[j][1] = v.y; wb[j][2] = v.z; wb[j][3] = v.w;
        }
        #pragma unroll
        for (int i = 0; i < 4; ++i)
            #pragma unroll
            for (int j = 0; j < 4; ++j)
                #pragma unroll
                for (int p = 0; p < 4; ++p)
                    acc[i][j] = fmaf(qa[i][p], wb[j][p], acc[i][j]);
    }

    float* dbase = dst + (size_t)bh * TD + (size_t)r0 * Dn;
    unsigned short* hbase = dsth + (size_t)bh * TD + (size_t)r0 * Dn;
    unsigned short* lbase = dstl + (size_t)bh * TD + (size_t)r0 * Dn;
    #pragma unroll
    for (int i = 0; i < 4; ++i) {
        size_t off = (size_t)(4 * ty + i) * Dn + 4 * tx;
        float4 o = make_float4(acc[i][0], acc[i][1], acc[i][2], acc[i][3]);
        *(float4*)&dbase[off] = o;
        ushort4 hv, lv;
        hv.x = bf16_rne(o.x); lv.x = bf16_rne(o.x - bf16_to_f(hv.x));
        hv.y = bf16_rne(o.y); lv.y = bf16_rne(o.y - bf16_to_f(hv.y));
        hv.z = bf16_rne(o.z); lv.z = bf16_rne(o.z - bf16_to_f(hv.z));
        hv.w = bf16_rne(o.w); lv.w = bf16_rne(o.w - bf16_to_f(hv.w));
        *(ushort4*)&hbase[off] = hv;
        *(ushort4*)&lbase[off] = lv;
    }
}

// ---------------------------------------------------------------------------
// K2: 128-row block sums of kf (fp32)
// ---------------------------------------------------------------------------
__global__ void k_blocksum(const float* __restrict__ kf1, const float* __restrict__ kf2,
                           float* __restrict__ bs) {
    __shared__ float red[4][64];
    int t  = threadIdx.x;
    int bx = blockIdx.x;
    int j  = bx & 7;
    int br = (bx >> 3) & 1;
    int bh = bx >> 4;
    const float* kf = (br ? kf2 : kf1) + (size_t)bh * TD + (size_t)j * 128 * Dn;
    int d = t & 63, rg = t >> 6;
    float p = 0.f;
    #pragma unroll 4
    for (int r = 0; r < 32; ++r) p += kf[(size_t)(rg * 32 + r) * Dn + d];
    red[rg][d] = p;
    __syncthreads();
    if (rg == 0)
        bs[(((size_t)bh * 2 + br) * 8 + j) * 64 + d] =
            red[0][d] + red[1][d] + red[2][d] + red[3][d];
}

// ---------------------------------------------------------------------------
// K3: exclusive prefix over the 8 block sums -> kc
// ---------------------------------------------------------------------------
__global__ void k_prefix(const float* __restrict__ bs, float* __restrict__ kc) {
    int bx = blockIdx.x;
    int br = bx & 1, bh = bx >> 1;
    int d = threadIdx.x;
    float run = 0.f;
    for (int j = 0; j < 8; ++j) {
        size_t idx = (((size_t)bh * 2 + br) * 8 + j) * 64 + d;
        kc[idx] = run;
        run += bs[idx];
    }
}

// ---------------------------------------------------------------------------
// K_s2: inv_s[bh,br,row] = 1 / ( qf[row] . Pref[min(row+1,1023)] ), fp32.
// One block per (bh,br,chunk of 128 rows); kf chunk staged in LDS; 4 waves
// each serial-walk 32 rows (seeded by intra-chunk wave sums).
// Block j dots rows [R0-1, R0+126]; row R0+127 is dotted by block j+1's
// first step (identical value); row 1023 by the j==7 tail.
// ---------------------------------------------------------------------------
__global__ __launch_bounds__(256) void k_s2(
    const float* __restrict__ qf1, const float* __restrict__ kf1,
    const float* __restrict__ qf2, const float* __restrict__ kf2,
    const float* __restrict__ kc,  float* __restrict__ inv_out) {

    __shared__ float kfl[128][64];
    __shared__ float wsum[4][64];

    int bx = blockIdx.x;            // 1024 = bh(64) x br(2) x j(8)
    int j = bx & 7, br = (bx >> 3) & 1, bh = bx >> 4;
    int t = threadIdx.x;
    int g = t >> 6, d = t & 63;
    int R0 = j * 128;

    const float* qf = (br ? qf2 : qf1) + (size_t)bh * TD;
    const float* kf = (br ? kf2 : kf1) + (size_t)bh * TD;

    #pragma unroll
    for (int it = 0; it < 8; ++it) {
        int f4 = it * 256 + t;       // 0..2047 float4s
        int r = f4 >> 4, c4 = (f4 & 15) << 2;
        *(float4*)&kfl[r][c4] = *(const float4*)&kf[(size_t)(R0 + r) * Dn + c4];
    }
    __syncthreads();

    float ps = 0.f;
    #pragma unroll 8
    for (int r = 0; r < 32; ++r) ps += kfl[g * 32 + r][d];
    wsum[g][d] = ps;
    __syncthreads();

    float run = kc[(((size_t)bh * 2 + br) * 8 + j) * 64 + d];
    #pragma unroll
    for (int g2 = 0; g2 < 3; ++g2) if (g2 < g) run += wsum[g2][d];

    float* inv = inv_out + ((size_t)bh * 2 + br) * Tn;

    #pragma unroll 4
    for (int s = 0; s < 32; ++s) {
        int a = g * 32 + s;
        run += kfl[a][d];            // run = Pref[R0 + a]
        int rr = R0 + a - 1;         // row whose denominator this is
        if (rr >= 0) {
            float dv = qf[(size_t)rr * Dn + d] * run;
            #pragma unroll
            for (int m = 1; m < 64; m <<= 1) dv += __shfl_xor(dv, m);
            if (d == 0) inv[rr] = 1.0f / dv;
        }
    }
    if (j == 7 && g == 3) {          // row 1023: Pref clamps at 1023
        float dv = qf[(size_t)1023 * Dn + d] * run;
        #pragma unroll
        for (int m = 1; m < 64; m <<= 1) dv += __shfl_xor(dv, m);
        if (d == 0) inv[1023] = 1.0f / dv;
    }
}

// ---------------------------------------------------------------------------
// K_tile (MFMA): one 128x128 tile per 512-thread block (8 waves, 32x64 each).
// Numerator via 3-term bf16 split (hh+hl+lh) with mfma_f32_16x16x32_bf16;
// per-branch accumulators combined as acc1*i1[r] - lam*acc2*i2[r] at write.
// A-frags straight from global; B hi/lo staged in LDS (80B row stride).
//   c < rt: full GEMM; c == rt: + mask; c > rt: coalesced zero-fill (+edge).
// grid 4096 = bh(64) x rt(8) x c(8), XCD-chunk swizzled.
// ---------------------------------------------------------------------------
__global__ __launch_bounds__(512, 4) void k_tile(
    const unsigned short* __restrict__ qh1, const unsigned short* __restrict__ ql1,
    const unsigned short* __restrict__ qh2, const unsigned short* __restrict__ ql2,
    const unsigned short* __restrict__ kh1, const unsigned short* __restrict__ kl1,
    const unsigned short* __restrict__ kh2, const unsigned short* __restrict__ kl2,
    const float* __restrict__ qf1, const float* __restrict__ qf2,
    const float* __restrict__ kf1, const float* __restrict__ kf2,
    const float* __restrict__ inv_g, const float* __restrict__ lamp,
    float* __restrict__ out) {

    __shared__ unsigned short Bhs[128 * 40];   // 80B row stride: banks 2-way (free)
    __shared__ unsigned short Bls[128 * 40];
    __shared__ float inv_lds[2][128];
    __shared__ float e_sh[2];

    int t  = threadIdx.x;
    int vid = (blockIdx.x & 7) * 512 + (blockIdx.x >> 3);   // XCD-chunk swizzle
    int bh = vid >> 6;
    int tile = vid & 63;
    int rt = tile >> 3, c = tile & 7;
    int r0 = rt * 128, cb = c * 128;

    const float lam = lamp[0];
    const size_t bb = (size_t)bh * TD;

    // ---------------- fill role ----------------
    if (c > rt) {
        float ev = 0.f;
        if (c == rt + 1) {
            if (t < 128) {
                int br = t >> 6, d = t & 63;
                const float* qp = (br ? qf2 : qf1) + bb;
                const float* kp = (br ? kf2 : kf1) + bb;
                float p = qp[(size_t)(r0 + 127) * Dn + d] * kp[(size_t)cb * Dn + d];
                #pragma unroll
                for (int m = 1; m < 64; m <<= 1) p += __shfl_xor(p, m);
                if (d == 0) e_sh[br] = p;
            }
            __syncthreads();
            float i1 = inv_g[((size_t)bh * 2 + 0) * Tn + r0 + 127];
            float i2 = inv_g[((size_t)bh * 2 + 1) * Tn + r0 + 127];
            ev = e_sh[0] * i1 - lam * (e_sh[1] * i2);
        }
        // fully-coalesced zero fill: flat float4 index within the 64KB tile
        float4 z = make_float4(0.f, 0.f, 0.f, 0.f);
        #pragma unroll
        for (int i = 0; i < 8; ++i) {
            int f = i * 512 + t;               // 0..4095 float4s
            int row = f >> 5, c4 = (f & 31) << 2;
            float4 o = z;
            if (c == rt + 1 && f == 4064) o.x = ev;   // (row 127, col 0)
            *(float4*)&out[((size_t)bh * Tn + r0 + row) * Tn + cb + c4] = o;
        }
        return;
    }

    // ---------------- compute role ----------------
    if (t < 256) {
        int br = t >> 7, row = t & 127;
        inv_lds[br][row] = inv_g[((size_t)bh * 2 + br) * Tn + r0 + row];
    }

    int w = t >> 6, l = t & 63;
    int wr = (w & 3) * 32;          // wave row offset (local)
    int wc = (w >> 2) * 64;         // wave col offset (local)
    int lrow = l & 15, lk = l >> 4; // frag lane decomposition

    f32x4 acc[2][2][4];             // [branch][rf][cf]
    #pragma unroll
    for (int b = 0; b < 2; ++b)
        #pragma unroll
        for (int rf = 0; rf < 2; ++rf)
            #pragma unroll
            for (int cf = 0; cf < 4; ++cf)
                acc[b][rf][cf] = (f32x4){0.f, 0.f, 0.f, 0.f};

    const unsigned short* qh[2] = { qh1 + bb, qh2 + bb };
    const unsigned short* ql[2] = { ql1 + bb, ql2 + bb };
    const unsigned short* khp[2] = { kh1 + bb, kh2 + bb };
    const unsigned short* klp[2] = { kl1 + bb, kl2 + bb };

    // staging mapping: 512 threads x 32B = 16KB per pass
    int sc = t & 127;               // column
    int sg = (t >> 7) & 1;          // 0 = hi, 1 = lo
    int sq = t >> 8;                // which 32B half of the 64B k-slice

    #pragma unroll
    for (int pass = 0; pass < 4; ++pass) {
        const int b = pass >> 1, s = pass & 1;
        __syncthreads();            // WAR on Bhs/Bls
        {
            const unsigned short* srcp =
                (sg ? klp[b] : khp[b]) + (size_t)(cb + sc) * Dn + s * 32 + sq * 16;
            bf16x8 v0 = *(const bf16x8*)srcp;
            bf16x8 v1 = *(const bf16x8*)(srcp + 8);
            unsigned short* dstp = (sg ? Bls : Bhs) + sc * 40 + sq * 16;
            *(bf16x8*)dstp = v0;
            *(bf16x8*)(dstp + 8) = v1;
        }
        __syncthreads();
        // A fragments (global; row = lane&15, k = (lane>>4)*8 contiguous)
        const unsigned short* aqh = qh[b] + (size_t)(r0 + wr + lrow) * Dn + s * 32 + lk * 8;
        const unsigned short* aql = ql[b] + (size_t)(r0 + wr + lrow) * Dn + s * 32 + lk * 8;
        bf16x8 ah0 = *(const bf16x8*)aqh;
        bf16x8 ah1 = *(const bf16x8*)(aqh + 16 * Dn);
        bf16x8 al0 = *(const bf16x8*)aql;
        bf16x8 al1 = *(const bf16x8*)(aql + 16 * Dn);
        #pragma unroll
        for (int cf = 0; cf < 4; ++cf) {
            int col = wc + cf * 16 + lrow;
            bf16x8 bhf = *(const bf16x8*)&Bhs[col * 40 + lk * 8];
            bf16x8 blf = *(const bf16x8*)&Bls[col * 40 + lk * 8];
            acc[b][0][cf] = __builtin_amdgcn_mfma_f32_16x16x32_bf16(ah0, bhf, acc[b][0][cf], 0, 0, 0);
            acc[b][0][cf] = __builtin_amdgcn_mfma_f32_16x16x32_bf16(ah0, blf, acc[b][0][cf], 0, 0, 0);
            acc[b][0][cf] = __builtin_amdgcn_mfma_f32_16x16x32_bf16(al0, bhf, acc[b][0][cf], 0, 0, 0);
            acc[b][1][cf] = __builtin_amdgcn_mfma_f32_16x16x32_bf16(ah1, bhf, acc[b][1][cf], 0, 0, 0);
            acc[b][1][cf] = __builtin_amdgcn_mfma_f32_16x16x32_bf16(ah1, blf, acc[b][1][cf], 0, 0, 0);
            acc[b][1][cf] = __builtin_amdgcn_mfma_f32_16x16x32_bf16(al1, bhf, acc[b][1][cf], 0, 0, 0);
        }
    }

    // mask + combine + write.  D layout: col = lane&15, row = (lane>>4)*4 + reg
    #pragma unroll
    for (int rf = 0; rf < 2; ++rf) {
        int rowb = wr + rf * 16 + lk * 4;    // local row base
        #pragma unroll
        for (int cf = 0; cf < 4; ++cf) {
            int col = cb + wc + cf * 16 + lrow;   // global col
            #pragma unroll
            for (int rg = 0; rg < 4; ++rg) {
                int lr = rowb + rg;
                int grow = r0 + lr;
                float v1 = acc[0][rf][cf][rg];
                float v2 = acc[1][rf][cf][rg];
                if (c == rt && col > grow + 1) { v1 = 0.f; v2 = 0.f; }
                float o = v1 * inv_lds[0][lr] - lam * (v2 * inv_lds[1][lr]);
                out[((size_t)bh * Tn + grow) * Tn + col] = o;
            }
        }
    }
}

// ---------------------------------------------------------------------------
extern "C" void kernel_launch(void* const* d_in, const int* in_sizes, int n_in,
                              void* d_out, int out_size, void* d_ws, size_t ws_size,
                              hipStream_t stream) {
    const float* q   = (const float*)d_in[0];
    const float* k   = (const float*)d_in[1];
    const float* W1q = (const float*)d_in[2];
    const float* W1k = (const float*)d_in[3];
    const float* W2q = (const float*)d_in[4];
    const float* W2k = (const float*)d_in[5];
    const float* lq1 = (const float*)d_in[6];
    const float* lk1 = (const float*)d_in[7];
    const float* lq2 = (const float*)d_in[8];
    const float* lk2 = (const float*)d_in[9];
    float* out = (float*)d_out;
    float* ws  = (float*)d_ws;

    float* qf1 = ws;
    float* kf1 = ws + (size_t)N4;
    float* qf2 = ws + 2 * (size_t)N4;
    float* kf2 = ws + 3 * (size_t)N4;
    unsigned short* us = (unsigned short*)(ws + 4 * (size_t)N4);
    unsigned short* qh1 = us;
    unsigned short* ql1 = us + 1 * (size_t)N4;
    unsigned short* kh1 = us + 2 * (size_t)N4;
    unsigned short* kl1 = us + 3 * (size_t)N4;
    unsigned short* qh2 = us + 4 * (size_t)N4;
    unsigned short* ql2 = us + 5 * (size_t)N4;
    unsigned short* kh2 = us + 6 * (size_t)N4;
    unsigned short* kl2 = us + 7 * (size_t)N4;
    float* bs  = ws + 8 * (size_t)N4;          // 8 ushort tensors == 4*N4 floats
    float* kc  = bs + 65536;
    float* lamp = kc + 65536;
    float* inv_s = lamp + 64;                  // 64*2*1024 floats

    k_lambda<<<1, 64, 0, stream>>>(lq1, lk1, lq2, lk2, lamp);
    k_proj4<<<4096, 256, 0, stream>>>(q, k, W1q, W1k, W2q, W2k,
                                      qf1, kf1, qf2, kf2,
                                      qh1, ql1, kh1, kl1, qh2, ql2, kh2, kl2);
    k_blocksum<<<1024, 256, 0, stream>>>(kf1, kf2, bs);
    k_prefix<<<128, 64, 0, stream>>>(bs, kc);
    k_s2<<<1024, 256, 0, stream>>>(qf1, kf1, qf2, kf2, kc, inv_s);
    k_tile<<<4096, 512, 0, stream>>>(qh1, ql1, qh2, ql2, kh1, kl1, kh2, kl2,
                                     qf1, qf2, kf1, kf2, inv_s, lamp, out);
}